// Round 1
// baseline (690.096 us; speedup 1.0000x reference)
//
#include <hip/hip_runtime.h>
#include <hip/hip_bf16.h>

#define H 24
#define L 4096
#define Dh 128
#define QBLK 128
#define KVBLK 64
#define NQT (L/QBLK)        // 32
#define NKT (L/KVBLK)       // 64
#define THREADS 512

typedef __bf16 bf16;
typedef bf16 bf16x8 __attribute__((ext_vector_type(8)));
typedef bf16 bf16x4 __attribute__((ext_vector_type(4)));
typedef bf16 bf16x2 __attribute__((ext_vector_type(2)));
typedef float f32x4 __attribute__((ext_vector_type(4)));

__device__ __forceinline__ void rope4(const float4& x, const float4& cs, float* o) {
  // x = (re0, im0, re1, im1), cs = (cos0, sin0, cos1, sin1)
  o[0] = x.x*cs.x - x.y*cs.y;
  o[1] = x.x*cs.y + x.y*cs.x;
  o[2] = x.z*cs.z - x.w*cs.w;
  o[3] = x.z*cs.w + x.w*cs.z;
}

// Pre-pass: RoPE(K)->bf16, V->bf16, same (h,pos,d) layout. 8 elems/thread.
__global__ __launch_bounds__(256) void prep_kernel(
    const float* __restrict__ k, const float* __restrict__ v,
    const float* __restrict__ pe, bf16* __restrict__ wk, bf16* __restrict__ wv) {
  int t = blockIdx.x * 256 + threadIdx.x;
  int base = t * 8;
  int d0  = base & (Dh - 1);
  int pos = (base >> 7) & (L - 1);
  const float4* kp = (const float4*)(k + base);
  const float4* pp = (const float4*)(pe + pos*Dh + d0);
  float4 a = kp[0], b = kp[1];
  float4 ca = pp[0], cb = pp[1];
  float o[8];
  rope4(a, ca, o); rope4(b, cb, o + 4);
  bf16x8 r;
#pragma unroll
  for (int j = 0; j < 8; j++) r[j] = (bf16)o[j];
  *(bf16x8*)(wk + base) = r;
  const float4* vp = (const float4*)(v + base);
  float4 va = vp[0], vb = vp[1];
  bf16x8 rv;
  rv[0]=(bf16)va.x; rv[1]=(bf16)va.y; rv[2]=(bf16)va.z; rv[3]=(bf16)va.w;
  rv[4]=(bf16)vb.x; rv[5]=(bf16)vb.y; rv[6]=(bf16)vb.z; rv[7]=(bf16)vb.w;
  *(bf16x8*)(wv + base) = rv;
}

// Flash attention. 8 waves, each owns 16 Q rows. KVBLK=64 streamed via LDS.
template<bool PRE>
__global__ __launch_bounds__(THREADS) void attn_kernel(
    const float* __restrict__ q, const float* __restrict__ kg,
    const float* __restrict__ vg, const float* __restrict__ pe,
    const bf16* __restrict__ wk, const bf16* __restrict__ wv,
    float* __restrict__ out) {
  // K tile, bf16 [64][128], XOR-swizzled: byte ^= (row&7)<<4  (G4 fix)
  __shared__ __align__(16) char KsB[KVBLK * Dh * 2];          // 16 KB
  // V^T tile, bf16 [128][72] (pad 64->72 keeps 16B row alignment, kills conflicts)
  __shared__ __align__(16) char VtB[Dh * (KVBLK + 8) * 2];    // 18 KB
  // per-wave P buffer, bf16 [16][64]
  __shared__ __align__(16) bf16 Ps[8][16 * KVBLK];            // 16 KB

  int bid = (int)blockIdx.x;
  int swz = (bid & 7) * (NQT * H / 8) + (bid >> 3);  // 96 consecutive per XCD
  int h  = swz >> 5;      // / NQT
  int qt = swz & 31;
  int tid = threadIdx.x;
  int w = tid >> 6, lane = tid & 63;
  int l16 = lane & 15, lg = lane >> 4;

  const float SC = 0.08838834764831845f * 1.4426950408889634f; // 1/sqrt(128)*log2(e)

  // ---- Q fragments: rope+scale once, keep in registers ----
  int qr = qt * QBLK + w * 16 + l16;
  bf16x8 qf[4];
  {
    const float* qrow  = q  + ((size_t)h * L + qr) * Dh;
    const float* perow = pe + (size_t)qr * Dh;
#pragma unroll
    for (int kk = 0; kk < 4; kk++) {
      int d = kk * 32 + lg * 8;
      float4 a  = *(const float4*)(qrow + d);
      float4 b  = *(const float4*)(qrow + d + 4);
      float4 ca = *(const float4*)(perow + d);
      float4 cb = *(const float4*)(perow + d + 4);
      float o[8]; rope4(a, ca, o); rope4(b, cb, o + 4);
#pragma unroll
      for (int j = 0; j < 8; j++) qf[kk][j] = (bf16)(o[j] * SC);
    }
  }

  float m[4], lsum[4];
  f32x4 acc[8];
#pragma unroll
  for (int r = 0; r < 4; r++) { m[r] = -3.0e38f; lsum[r] = 0.f; }
#pragma unroll
  for (int j = 0; j < 8; j++) acc[j] = (f32x4){0.f, 0.f, 0.f, 0.f};

  // staging work split
  int krow_s = tid >> 3;          // 0..63
  int kd_s   = (tid & 7) * 16;    // 0..112
  int vd_s   = (tid & 31) * 4;    // 0..124
  int vp_s   = tid >> 5;          // 0..15

  for (int t = 0; t < NKT; t++) {
    int kv0 = t * KVBLK;
    // ---- stage K (rope if !PRE) into swizzled LDS ----
    {
      bf16 ko[16];
      if constexpr (PRE) {
        const bf16* src = wk + ((size_t)h * L + kv0 + krow_s) * Dh + kd_s;
        *(bf16x8*)ko       = *(const bf16x8*)src;
        *(bf16x8*)(ko + 8) = *(const bf16x8*)(src + 8);
      } else {
        const float* src = kg + ((size_t)h * L + kv0 + krow_s) * Dh + kd_s;
        const float* ps  = pe + (size_t)(kv0 + krow_s) * Dh + kd_s;
#pragma unroll
        for (int c = 0; c < 4; c++) {
          float4 a  = *(const float4*)(src + c * 4);
          float4 cs = *(const float4*)(ps + c * 4);
          float o[4]; rope4(a, cs, o);
          ko[c*4+0]=(bf16)o[0]; ko[c*4+1]=(bf16)o[1];
          ko[c*4+2]=(bf16)o[2]; ko[c*4+3]=(bf16)o[3];
        }
      }
#pragma unroll
      for (int c = 0; c < 2; c++) {
        int byte = (krow_s * 256 + (kd_s + c * 8) * 2) ^ ((krow_s & 7) << 4);
        *(bf16x8*)(KsB + byte) = *(bf16x8*)(ko + c * 8);
      }
    }
    // ---- stage V transposed into LDS ----
    {
#pragma unroll
      for (int pi = 0; pi < 2; pi++) {
        int p = vp_s + pi * 16;       // 0..31
        int r0 = 2 * p;
        bf16x4 a4, b4;
        if constexpr (PRE) {
          a4 = *(const bf16x4*)(wv + ((size_t)h * L + kv0 + r0)     * Dh + vd_s);
          b4 = *(const bf16x4*)(wv + ((size_t)h * L + kv0 + r0 + 1) * Dh + vd_s);
        } else {
          float4 fa = *(const float4*)(vg + ((size_t)h * L + kv0 + r0)     * Dh + vd_s);
          float4 fb = *(const float4*)(vg + ((size_t)h * L + kv0 + r0 + 1) * Dh + vd_s);
          a4[0]=(bf16)fa.x; a4[1]=(bf16)fa.y; a4[2]=(bf16)fa.z; a4[3]=(bf16)fa.w;
          b4[0]=(bf16)fb.x; b4[1]=(bf16)fb.y; b4[2]=(bf16)fb.z; b4[3]=(bf16)fb.w;
        }
#pragma unroll
        for (int j = 0; j < 4; j++) {
          bf16x2 pr; pr[0] = a4[j]; pr[1] = b4[j];
          *(bf16x2*)(VtB + (vd_s + j) * 144 + r0 * 2) = pr;  // 144 = 72*2, 16B-mult
        }
      }
    }
    __syncthreads();

    // ---- QK^T: S[16][64] per wave ----
    f32x4 s[4];
#pragma unroll
    for (int jt = 0; jt < 4; jt++) {
      f32x4 a_s = (f32x4){0.f, 0.f, 0.f, 0.f};
      int krow = jt * 16 + l16;
#pragma unroll
      for (int kk = 0; kk < 4; kk++) {
        int byte = (krow * 256 + (kk * 32 + lg * 8) * 2) ^ ((krow & 7) << 4);
        bf16x8 kf = *(const bf16x8*)(KsB + byte);
        a_s = __builtin_amdgcn_mfma_f32_16x16x32_bf16(qf[kk], kf, a_s, 0, 0, 0);
      }
      s[jt] = a_s;
    }

    // ---- online softmax (exp2 domain) ----
#pragma unroll
    for (int r = 0; r < 4; r++) {
      float tm = fmaxf(fmaxf(s[0][r], s[1][r]), fmaxf(s[2][r], s[3][r]));
#pragma unroll
      for (int off = 1; off < 16; off <<= 1) tm = fmaxf(tm, __shfl_xor(tm, off, 64));
      float mn = fmaxf(m[r], tm);
      float alpha = exp2f(m[r] - mn);
      m[r] = mn;
      float rs = 0.f;
#pragma unroll
      for (int jt = 0; jt < 4; jt++) {
        float pv_ = exp2f(s[jt][r] - mn);
        s[jt][r] = pv_;
        rs += pv_;
      }
#pragma unroll
      for (int off = 1; off < 16; off <<= 1) rs += __shfl_xor(rs, off, 64);
      lsum[r] = lsum[r] * alpha + rs;
#pragma unroll
      for (int j = 0; j < 8; j++) acc[j][r] *= alpha;
    }

    // ---- P: C/D layout -> A-fragment layout via per-wave LDS bounce ----
#pragma unroll
    for (int jt = 0; jt < 4; jt++)
#pragma unroll
      for (int r = 0; r < 4; r++)
        Ps[w][(lg * 4 + r) * KVBLK + jt * 16 + l16] = (bf16)s[jt][r];
    __syncthreads();

    bf16x8 pf0 = *(const bf16x8*)&Ps[w][l16 * KVBLK + lg * 8];
    bf16x8 pf1 = *(const bf16x8*)&Ps[w][l16 * KVBLK + 32 + lg * 8];
    // ---- PV ----
#pragma unroll
    for (int jt = 0; jt < 8; jt++) {
      bf16x8 vf0 = *(const bf16x8*)(VtB + (jt * 16 + l16) * 144 + (lg * 8) * 2);
      acc[jt] = __builtin_amdgcn_mfma_f32_16x16x32_bf16(pf0, vf0, acc[jt], 0, 0, 0);
      bf16x8 vf1 = *(const bf16x8*)(VtB + (jt * 16 + l16) * 144 + (32 + lg * 8) * 2);
      acc[jt] = __builtin_amdgcn_mfma_f32_16x16x32_bf16(pf1, vf1, acc[jt], 0, 0, 0);
    }
    __syncthreads();
  }

  // ---- epilogue: normalize + write (b, L, H*D) ----
  float linv[4];
#pragma unroll
  for (int r = 0; r < 4; r++) linv[r] = 1.0f / lsum[r];
  int orow_base = qt * QBLK + w * 16 + lg * 4;
#pragma unroll
  for (int jt = 0; jt < 8; jt++) {
    int col = h * Dh + jt * 16 + l16;
#pragma unroll
    for (int r = 0; r < 4; r++) {
      out[(size_t)(orow_base + r) * (H * Dh) + col] = acc[jt][r] * linv[r];
    }
  }
}

extern "C" void kernel_launch(void* const* d_in, const int* in_sizes, int n_in,
                              void* d_out, int out_size, void* d_ws, size_t ws_size,
                              hipStream_t stream) {
  const float* q  = (const float*)d_in[0];
  const float* k  = (const float*)d_in[1];
  const float* v  = (const float*)d_in[2];
  const float* pe = (const float*)d_in[3];
  float* out = (float*)d_out;
  const size_t elems = (size_t)H * L * Dh;       // 12,582,912
  const size_t need  = 2 * elems * sizeof(unsigned short); // 50.3 MB
  if (ws_size >= need) {
    bf16* wk = (bf16*)d_ws;
    bf16* wv = wk + elems;
    prep_kernel<<<(int)(elems / 8 / 256), 256, 0, stream>>>(k, v, pe, wk, wv);
    attn_kernel<true><<<H * NQT, THREADS, 0, stream>>>(q, k, v, pe, wk, wv, out);
  } else {
    attn_kernel<false><<<H * NQT, THREADS, 0, stream>>>(q, k, v, pe, nullptr, nullptr, out);
  }
}

// Round 2
// 559.996 us; speedup vs baseline: 1.2323x; 1.2323x over previous
//
#include <hip/hip_runtime.h>
#include <hip/hip_bf16.h>

#define H 24
#define L 4096
#define Dh 128
#define QBLK 128
#define KVBLK 64
#define NQT (L/QBLK)        // 32
#define NKT (L/KVBLK)       // 64
#define THREADS 512

typedef __bf16 bf16;
typedef bf16 bf16x8 __attribute__((ext_vector_type(8)));
typedef bf16 bf16x4 __attribute__((ext_vector_type(4)));
typedef bf16 bf16x2 __attribute__((ext_vector_type(2)));
typedef float f32x4 __attribute__((ext_vector_type(4)));

__device__ __forceinline__ void rope4(const float4& x, const float4& cs, float* o) {
  o[0] = x.x*cs.x - x.y*cs.y;
  o[1] = x.x*cs.y + x.y*cs.x;
  o[2] = x.z*cs.z - x.w*cs.w;
  o[3] = x.z*cs.w + x.w*cs.z;
}

// Pre-pass 1: RoPE(K)->bf16, same (h,pos,d) layout. 8 elems/thread.
__global__ __launch_bounds__(256) void prep_kernel(
    const float* __restrict__ k, const float* __restrict__ pe,
    bf16* __restrict__ wk) {
  int t = blockIdx.x * 256 + threadIdx.x;
  int base = t * 8;
  int d0  = base & (Dh - 1);
  int pos = (base >> 7) & (L - 1);
  const float4* kp = (const float4*)(k + base);
  const float4* pp = (const float4*)(pe + pos*Dh + d0);
  float4 a = kp[0], b = kp[1];
  float4 ca = pp[0], cb = pp[1];
  float o[8];
  rope4(a, ca, o); rope4(b, cb, o + 4);
  bf16x8 r;
#pragma unroll
  for (int j = 0; j < 8; j++) r[j] = (bf16)o[j];
  *(bf16x8*)(wk + base) = r;
}

// Pre-pass 2: V -> V^T bf16, wv layout [H][Dh][L]. 64x64 tiles via LDS.
__global__ __launch_bounds__(256) void vtrans_kernel(
    const float* __restrict__ v, bf16* __restrict__ wv) {
  __shared__ bf16 T[64][68];
  int b = blockIdx.x;          // H * (L/64) * (Dh/64) = 24*64*2
  int dt = b & 1;
  int pt = (b >> 1) & 63;
  int h  = b >> 7;
  int t = threadIdx.x;
  int P0 = pt * 64, D0 = dt * 64;
#pragma unroll
  for (int i = 0; i < 4; i++) {
    int pos_l = (t >> 4) + 16 * i;
    int d_l = (t & 15) * 4;
    float4 a = *(const float4*)(v + ((size_t)h * L + P0 + pos_l) * Dh + D0 + d_l);
    T[pos_l][d_l+0] = (bf16)a.x; T[pos_l][d_l+1] = (bf16)a.y;
    T[pos_l][d_l+2] = (bf16)a.z; T[pos_l][d_l+3] = (bf16)a.w;
  }
  __syncthreads();
#pragma unroll
  for (int i = 0; i < 4; i++) {
    int d_l = (t >> 4) + 16 * i;
    int pos_l = (t & 15) * 4;
    bf16x4 o;
#pragma unroll
    for (int j = 0; j < 4; j++) o[j] = T[pos_l + j][d_l];
    *(bf16x4*)(wv + ((size_t)h * Dh + D0 + d_l) * L + P0 + pos_l) = o;
  }
}

// Flash attention. 8 waves, each owns 16 Q rows. KVBLK=64 streamed via LDS.
template<bool PRE>
__global__ __launch_bounds__(THREADS) void attn_kernel(
    const float* __restrict__ q, const float* __restrict__ kg,
    const float* __restrict__ vg, const float* __restrict__ pe,
    const bf16* __restrict__ wk, const bf16* __restrict__ wv,
    float* __restrict__ out) {
  // K tile, bf16 [64][128], XOR-swizzled: byte ^= (row&7)<<4
  __shared__ __align__(16) char KsB[KVBLK * Dh * 2];          // 16 KB
  // V^T tile, bf16 [128][72] (pad 64->72: 144B row, 16B-aligned)
  __shared__ __align__(16) char VtB[Dh * (KVBLK + 8) * 2];    // 18 KB
  // per-wave P buffer, bf16 [16][64], XOR-swizzled rows
  __shared__ __align__(16) bf16 Ps[8][16 * KVBLK];            // 16 KB

  int bid = (int)blockIdx.x;
  int swz = (bid & 7) * (NQT * H / 8) + (bid >> 3);  // 96 consecutive per XCD
  int h  = swz >> 5;
  int qt = swz & 31;
  int tid = threadIdx.x;
  int w = tid >> 6, lane = tid & 63;
  int l16 = lane & 15, lg = lane >> 4;

  const float SC = 0.08838834764831845f * 1.4426950408889634f; // 1/sqrt(128)*log2(e)

  // ---- Q fragments: rope+scale once, keep in registers ----
  int qr = qt * QBLK + w * 16 + l16;
  bf16x8 qf[4];
  {
    const float* qrow  = q  + ((size_t)h * L + qr) * Dh;
    const float* perow = pe + (size_t)qr * Dh;
#pragma unroll
    for (int kk = 0; kk < 4; kk++) {
      int d = kk * 32 + lg * 8;
      float4 a  = *(const float4*)(qrow + d);
      float4 b  = *(const float4*)(qrow + d + 4);
      float4 ca = *(const float4*)(perow + d);
      float4 cb = *(const float4*)(perow + d + 4);
      float o[8]; rope4(a, ca, o); rope4(b, cb, o + 4);
#pragma unroll
      for (int j = 0; j < 8; j++) qf[kk][j] = (bf16)(o[j] * SC);
    }
  }

  float m[4], lsum[4];
  f32x4 acc[8];
#pragma unroll
  for (int r = 0; r < 4; r++) { m[r] = -3.0e38f; lsum[r] = 0.f; }
#pragma unroll
  for (int j = 0; j < 8; j++) acc[j] = (f32x4){0.f, 0.f, 0.f, 0.f};

  // staging work split
  int krow_s = tid >> 3;          // 0..63  (K rows)
  int kd_s   = (tid & 7) * 16;    // 0..112 (K cols)
  int vd2    = tid >> 2;          // 0..127 (V^T rows, PRE path)
  int vc2    = (tid & 3) * 16;    // 0,16,32,48 (V^T cols, PRE path)
  int vd_s   = (tid & 31) * 4;    // !PRE path
  int vp_s   = tid >> 5;          // !PRE path

  char* psb = (char*)&Ps[w][0];

  for (int t = 0; t < NKT; t++) {
    int kv0 = t * KVBLK;
    // ---- stage K (rope if !PRE) into swizzled LDS ----
    {
      bf16 ko[16];
      if constexpr (PRE) {
        const bf16* src = wk + ((size_t)h * L + kv0 + krow_s) * Dh + kd_s;
        *(bf16x8*)ko       = *(const bf16x8*)src;
        *(bf16x8*)(ko + 8) = *(const bf16x8*)(src + 8);
      } else {
        const float* src = kg + ((size_t)h * L + kv0 + krow_s) * Dh + kd_s;
        const float* ps  = pe + (size_t)(kv0 + krow_s) * Dh + kd_s;
#pragma unroll
        for (int c = 0; c < 4; c++) {
          float4 a  = *(const float4*)(src + c * 4);
          float4 cs = *(const float4*)(ps + c * 4);
          float o[4]; rope4(a, cs, o);
          ko[c*4+0]=(bf16)o[0]; ko[c*4+1]=(bf16)o[1];
          ko[c*4+2]=(bf16)o[2]; ko[c*4+3]=(bf16)o[3];
        }
      }
#pragma unroll
      for (int c = 0; c < 2; c++) {
        int byte = (krow_s * 256 + (kd_s + c * 8) * 2) ^ ((krow_s & 7) << 4);
        *(bf16x8*)(KsB + byte) = *(bf16x8*)(ko + c * 8);
      }
    }
    // ---- stage V^T tile ----
    if constexpr (PRE) {
      // wv is V^T [H][Dh][L]: contiguous bf16x8 copies, conflict-free
      const bf16* vsrc = wv + ((size_t)h * Dh + vd2) * L + kv0 + vc2;
      *(bf16x8*)(VtB + vd2 * 144 + vc2 * 2)      = *(const bf16x8*)(vsrc);
      *(bf16x8*)(VtB + vd2 * 144 + vc2 * 2 + 16) = *(const bf16x8*)(vsrc + 8);
    } else {
#pragma unroll
      for (int pi = 0; pi < 2; pi++) {
        int p = vp_s + pi * 16;
        int r0 = 2 * p;
        float4 fa = *(const float4*)(vg + ((size_t)h * L + kv0 + r0)     * Dh + vd_s);
        float4 fb = *(const float4*)(vg + ((size_t)h * L + kv0 + r0 + 1) * Dh + vd_s);
        bf16x4 a4, b4;
        a4[0]=(bf16)fa.x; a4[1]=(bf16)fa.y; a4[2]=(bf16)fa.z; a4[3]=(bf16)fa.w;
        b4[0]=(bf16)fb.x; b4[1]=(bf16)fb.y; b4[2]=(bf16)fb.z; b4[3]=(bf16)fb.w;
#pragma unroll
        for (int j = 0; j < 4; j++) {
          bf16x2 pr; pr[0] = a4[j]; pr[1] = b4[j];
          *(bf16x2*)(VtB + (vd_s + j) * 144 + r0 * 2) = pr;
        }
      }
    }
    __syncthreads();

    // ---- QK^T: S[16][64] per wave ----
    f32x4 s[4];
#pragma unroll
    for (int jt = 0; jt < 4; jt++) {
      f32x4 a_s = (f32x4){0.f, 0.f, 0.f, 0.f};
      int krow = jt * 16 + l16;
#pragma unroll
      for (int kk = 0; kk < 4; kk++) {
        int byte = (krow * 256 + (kk * 32 + lg * 8) * 2) ^ ((krow & 7) << 4);
        bf16x8 kf = *(const bf16x8*)(KsB + byte);
        a_s = __builtin_amdgcn_mfma_f32_16x16x32_bf16(qf[kk], kf, a_s, 0, 0, 0);
      }
      s[jt] = a_s;
    }

    // ---- online softmax (exp2 domain) ----
#pragma unroll
    for (int r = 0; r < 4; r++) {
      float tm = fmaxf(fmaxf(s[0][r], s[1][r]), fmaxf(s[2][r], s[3][r]));
#pragma unroll
      for (int off = 1; off < 16; off <<= 1) tm = fmaxf(tm, __shfl_xor(tm, off, 64));
      float mn = fmaxf(m[r], tm);
      float alpha = exp2f(m[r] - mn);
      m[r] = mn;
      float rs = 0.f;
#pragma unroll
      for (int jt = 0; jt < 4; jt++) {
        float pv_ = exp2f(s[jt][r] - mn);
        s[jt][r] = pv_;
        rs += pv_;
      }
#pragma unroll
      for (int off = 1; off < 16; off <<= 1) rs += __shfl_xor(rs, off, 64);
      lsum[r] = lsum[r] * alpha + rs;
#pragma unroll
      for (int j = 0; j < 8; j++) acc[j][r] *= alpha;
    }

    // ---- P: C/D layout -> A-fragment layout via per-wave swizzled LDS bounce ----
#pragma unroll
    for (int jt = 0; jt < 4; jt++)
#pragma unroll
      for (int r = 0; r < 4; r++) {
        int row = lg * 4 + r;
        int byte = (row * 128 + (jt * 16 + l16) * 2) ^ ((row & 7) << 4);
        *(bf16*)(psb + byte) = (bf16)s[jt][r];
      }
    // wave-private buffer: no block barrier needed, just drain LDS writes
    asm volatile("s_waitcnt lgkmcnt(0)" ::: "memory");
    int pb0 = (l16 * 128 + lg * 16) ^ ((l16 & 7) << 4);
    int pb1 = (l16 * 128 + 64 + lg * 16) ^ ((l16 & 7) << 4);
    bf16x8 pf0 = *(const bf16x8*)(psb + pb0);
    bf16x8 pf1 = *(const bf16x8*)(psb + pb1);

    // ---- PV ----
#pragma unroll
    for (int jt = 0; jt < 8; jt++) {
      bf16x8 vf0 = *(const bf16x8*)(VtB + (jt * 16 + l16) * 144 + (lg * 8) * 2);
      acc[jt] = __builtin_amdgcn_mfma_f32_16x16x32_bf16(pf0, vf0, acc[jt], 0, 0, 0);
      bf16x8 vf1 = *(const bf16x8*)(VtB + (jt * 16 + l16) * 144 + (32 + lg * 8) * 2);
      acc[jt] = __builtin_amdgcn_mfma_f32_16x16x32_bf16(pf1, vf1, acc[jt], 0, 0, 0);
    }
    __syncthreads();
  }

  // ---- epilogue: normalize + write (b, L, H*D) ----
  float linv[4];
#pragma unroll
  for (int r = 0; r < 4; r++) linv[r] = 1.0f / lsum[r];
  int orow_base = qt * QBLK + w * 16 + lg * 4;
#pragma unroll
  for (int jt = 0; jt < 8; jt++) {
    int col = h * Dh + jt * 16 + l16;
#pragma unroll
    for (int r = 0; r < 4; r++) {
      out[(size_t)(orow_base + r) * (H * Dh) + col] = acc[jt][r] * linv[r];
    }
  }
}

extern "C" void kernel_launch(void* const* d_in, const int* in_sizes, int n_in,
                              void* d_out, int out_size, void* d_ws, size_t ws_size,
                              hipStream_t stream) {
  const float* q  = (const float*)d_in[0];
  const float* k  = (const float*)d_in[1];
  const float* v  = (const float*)d_in[2];
  const float* pe = (const float*)d_in[3];
  float* out = (float*)d_out;
  const size_t elems = (size_t)H * L * Dh;       // 12,582,912
  const size_t need  = 2 * elems * sizeof(unsigned short); // 50.3 MB
  if (ws_size >= need) {
    bf16* wk = (bf16*)d_ws;
    bf16* wv = wk + elems;
    prep_kernel<<<(int)(elems / 8 / 256), 256, 0, stream>>>(k, pe, wk);
    vtrans_kernel<<<H * (L / 64) * (Dh / 64), 256, 0, stream>>>(v, wv);
    attn_kernel<true><<<H * NQT, THREADS, 0, stream>>>(q, k, v, pe, wk, wv, out);
  } else {
    attn_kernel<false><<<H * NQT, THREADS, 0, stream>>>(q, k, v, pe, nullptr, nullptr, out);
  }
}

// Round 3
// 498.147 us; speedup vs baseline: 1.3853x; 1.1242x over previous
//
#include <hip/hip_runtime.h>
#include <hip/hip_bf16.h>

#define H 24
#define L 4096
#define Dh 128
#define QBLK 128
#define KVBLK 64
#define NQT (L/QBLK)        // 32
#define NKT (L/KVBLK)       // 64
#define THREADS 512

typedef __bf16 bf16;
typedef bf16 bf16x8 __attribute__((ext_vector_type(8)));
typedef bf16 bf16x4 __attribute__((ext_vector_type(4)));
typedef bf16 bf16x2 __attribute__((ext_vector_type(2)));
typedef float f32x4 __attribute__((ext_vector_type(4)));

__device__ __forceinline__ void rope4(const float4& x, const float4& cs, float* o) {
  o[0] = x.x*cs.x - x.y*cs.y;
  o[1] = x.x*cs.y + x.y*cs.x;
  o[2] = x.z*cs.z - x.w*cs.w;
  o[3] = x.z*cs.w + x.w*cs.z;
}

// Pre-pass 1: RoPE(K)->bf16, same (h,pos,d) layout.
__global__ __launch_bounds__(256) void prep_kernel(
    const float* __restrict__ k, const float* __restrict__ pe,
    bf16* __restrict__ wk) {
  int t = blockIdx.x * 256 + threadIdx.x;
  int base = t * 8;
  int d0  = base & (Dh - 1);
  int pos = (base >> 7) & (L - 1);
  const float4* kp = (const float4*)(k + base);
  const float4* pp = (const float4*)(pe + pos*Dh + d0);
  float4 a = kp[0], b = kp[1];
  float4 ca = pp[0], cb = pp[1];
  float o[8];
  rope4(a, ca, o); rope4(b, cb, o + 4);
  bf16x8 r;
#pragma unroll
  for (int j = 0; j < 8; j++) r[j] = (bf16)o[j];
  *(bf16x8*)(wk + base) = r;
}

// Pre-pass 2: V -> V^T bf16, wv layout [H][Dh][L].
__global__ __launch_bounds__(256) void vtrans_kernel(
    const float* __restrict__ v, bf16* __restrict__ wv) {
  __shared__ bf16 T[64][68];
  int b = blockIdx.x;
  int dt = b & 1;
  int pt = (b >> 1) & 63;
  int h  = b >> 7;
  int t = threadIdx.x;
  int P0 = pt * 64, D0 = dt * 64;
#pragma unroll
  for (int i = 0; i < 4; i++) {
    int pos_l = (t >> 4) + 16 * i;
    int d_l = (t & 15) * 4;
    float4 a = *(const float4*)(v + ((size_t)h * L + P0 + pos_l) * Dh + D0 + d_l);
    T[pos_l][d_l+0] = (bf16)a.x; T[pos_l][d_l+1] = (bf16)a.y;
    T[pos_l][d_l+2] = (bf16)a.z; T[pos_l][d_l+3] = (bf16)a.w;
  }
  __syncthreads();
#pragma unroll
  for (int i = 0; i < 4; i++) {
    int d_l = (t >> 4) + 16 * i;
    int pos_l = (t & 15) * 4;
    bf16x4 o;
#pragma unroll
    for (int j = 0; j < 4; j++) o[j] = T[pos_l + j][d_l];
    *(bf16x4*)(wv + ((size_t)h * Dh + D0 + d_l) * L + P0 + pos_l) = o;
  }
}

// ---- pipelined flash attention (PRE path) ----
// 8 waves x 16 Q-rows; KVBLK=64; LDS double-buffered; 1 raw barrier/iter.
__global__ __launch_bounds__(THREADS) void attn_pipe(
    const float* __restrict__ q, const float* __restrict__ pe,
    const bf16* __restrict__ wk, const bf16* __restrict__ wv,
    float* __restrict__ out) {
  __shared__ __align__(16) char KsB[2][KVBLK * Dh * 2];   // 2 x 16 KB, XOR-swz
  __shared__ __align__(16) char VtB[2][Dh * KVBLK * 2];   // 2 x 16 KB, XOR-swz
  __shared__ __align__(16) bf16 Ps[8][16 * KVBLK];        // 16 KB, per-wave

  int bid = (int)blockIdx.x;
  int swz = (bid & 7) * (NQT * H / 8) + (bid >> 3);
  int h  = swz >> 5;
  int qt = swz & 31;
  int tid = threadIdx.x;
  int w = tid >> 6, lane = tid & 63;
  int l16 = lane & 15, lg = lane >> 4;
  int swl = (l16 & 7) << 4;   // row-XOR swizzle term for reads (row&7 == l16&7)

  const float SC = 0.08838834764831845f * 1.4426950408889634f; // 1/sqrt(128)*log2e

  // ---- Q fragments: rope+scale once ----
  int qr = qt * QBLK + w * 16 + l16;
  bf16x8 qf[4];
  {
    const float* qrow  = q  + ((size_t)h * L + qr) * Dh;
    const float* perow = pe + (size_t)qr * Dh;
#pragma unroll
    for (int kk = 0; kk < 4; kk++) {
      int d = kk * 32 + lg * 8;
      float4 a  = *(const float4*)(qrow + d);
      float4 b  = *(const float4*)(qrow + d + 4);
      float4 ca = *(const float4*)(perow + d);
      float4 cb = *(const float4*)(perow + d + 4);
      float o[8]; rope4(a, ca, o); rope4(b, cb, o + 4);
#pragma unroll
      for (int j = 0; j < 8; j++) qf[kk][j] = (bf16)(o[j] * SC);
    }
  }

  float m[4], lsum[4];
  f32x4 acc[8];
#pragma unroll
  for (int r = 0; r < 4; r++) { m[r] = -3.0e38f; lsum[r] = 0.f; }
#pragma unroll
  for (int j = 0; j < 8; j++) acc[j] = (f32x4){0.f, 0.f, 0.f, 0.f};

  // ---- staging addressing ----
  int krow_s = tid >> 3;          // 0..63
  int kd_s   = (tid & 7) * 16;    // 0..112
  int kb0 = (krow_s * 256 + kd_s * 2)      ^ ((krow_s & 7) << 4);
  int kb1 = (krow_s * 256 + kd_s * 2 + 16) ^ ((krow_s & 7) << 4);
  const bf16* ksrc = wk + ((size_t)h * L + krow_s) * Dh + kd_s;

  int vrow_s = tid >> 2;          // 0..127 (d)
  int vcol_s = (tid & 3) * 16;    // 0,16,32,48 (pos)
  int vb0 = vrow_s * 128 + ((vcol_s * 2)      ^ ((vrow_s & 7) << 4));
  int vb1 = vrow_s * 128 + ((vcol_s * 2 + 16) ^ ((vrow_s & 7) << 4));
  const bf16* vsrc = wv + ((size_t)h * Dh + vrow_s) * L + vcol_s;

  // preload tile 0 into regs
  bf16x8 stk0 = *(const bf16x8*)(ksrc);
  bf16x8 stk1 = *(const bf16x8*)(ksrc + 8);
  bf16x8 stv0 = *(const bf16x8*)(vsrc);
  bf16x8 stv1 = *(const bf16x8*)(vsrc + 8);
  ksrc += (size_t)KVBLK * Dh;
  vsrc += KVBLK;

  char* psb = (char*)&Ps[w][0];
  int cur = 0;

  for (int t = 0; t < NKT; t++) {
    char* Kb = KsB[cur];
    char* Vb = VtB[cur];
    // write staged regs -> LDS buf[cur]
    *(bf16x8*)(Kb + kb0) = stk0;
    *(bf16x8*)(Kb + kb1) = stk1;
    *(bf16x8*)(Vb + vb0) = stv0;
    *(bf16x8*)(Vb + vb1) = stv1;
    // issue next tile's global loads (fly across the barrier; regs are private)
    if (t + 1 < NKT) {
      stk0 = *(const bf16x8*)(ksrc);
      stk1 = *(const bf16x8*)(ksrc + 8);
      stv0 = *(const bf16x8*)(vsrc);
      stv1 = *(const bf16x8*)(vsrc + 8);
      ksrc += (size_t)KVBLK * Dh;
      vsrc += KVBLK;
    }
    // barrier: only LDS writes must be visible (NOT vmcnt -> loads stay in flight)
    asm volatile("s_waitcnt lgkmcnt(0)" ::: "memory");
    __builtin_amdgcn_s_barrier();
    __builtin_amdgcn_sched_barrier(0);

    // ---- QK^T: S[16][64] per wave ----
    f32x4 s[4];
    __builtin_amdgcn_s_setprio(1);
#pragma unroll
    for (int jt = 0; jt < 4; jt++) {
      f32x4 a_s = (f32x4){0.f, 0.f, 0.f, 0.f};
      int krow = jt * 16 + l16;
#pragma unroll
      for (int kk = 0; kk < 4; kk++) {
        int byte = krow * 256 + ((kk * 64 + lg * 16) ^ swl);
        bf16x8 kf = *(const bf16x8*)(Kb + byte);
        a_s = __builtin_amdgcn_mfma_f32_16x16x32_bf16(qf[kk], kf, a_s, 0, 0, 0);
      }
      s[jt] = a_s;
    }
    __builtin_amdgcn_s_setprio(0);

    // ---- online softmax (exp2 domain, defer-max THR=8) ----
    float tm[4];
#pragma unroll
    for (int r = 0; r < 4; r++) {
      float t0 = fmaxf(fmaxf(s[0][r], s[1][r]), fmaxf(s[2][r], s[3][r]));
#pragma unroll
      for (int off = 1; off < 16; off <<= 1) t0 = fmaxf(t0, __shfl_xor(t0, off, 64));
      tm[r] = t0;
    }
    bool grow = (tm[0] > m[0] + 8.f) || (tm[1] > m[1] + 8.f) ||
                (tm[2] > m[2] + 8.f) || (tm[3] > m[3] + 8.f);
    if (__any(grow)) {
#pragma unroll
      for (int r = 0; r < 4; r++) {
        float mn = fmaxf(m[r], tm[r]);
        float alpha = exp2f(m[r] - mn);
        m[r] = mn;
        lsum[r] *= alpha;
#pragma unroll
        for (int j = 0; j < 8; j++) acc[j][r] *= alpha;
      }
    }
#pragma unroll
    for (int r = 0; r < 4; r++) {
      float rs = 0.f;
#pragma unroll
      for (int jt = 0; jt < 4; jt++) {
        float pv_ = exp2f(s[jt][r] - m[r]);
        s[jt][r] = pv_;
        rs += pv_;
      }
#pragma unroll
      for (int off = 1; off < 16; off <<= 1) rs += __shfl_xor(rs, off, 64);
      lsum[r] += rs;
    }

    // ---- P: C/D -> A-frag via per-wave swizzled LDS bounce ----
#pragma unroll
    for (int jt = 0; jt < 4; jt++)
#pragma unroll
      for (int r = 0; r < 4; r++) {
        int row = lg * 4 + r;
        int byte = (row * 128 + (jt * 16 + l16) * 2) ^ ((row & 7) << 4);
        *(bf16*)(psb + byte) = (bf16)s[jt][r];
      }
    asm volatile("s_waitcnt lgkmcnt(0)" ::: "memory");
    int pb0 = (l16 * 128 + lg * 16) ^ swl;
    int pb1 = (l16 * 128 + 64 + lg * 16) ^ swl;
    bf16x8 pf0 = *(const bf16x8*)(psb + pb0);
    bf16x8 pf1 = *(const bf16x8*)(psb + pb1);

    // ---- PV ----
    __builtin_amdgcn_s_setprio(1);
#pragma unroll
    for (int jt = 0; jt < 8; jt++) {
      int vrow = jt * 16 + l16;
      bf16x8 vf0 = *(const bf16x8*)(Vb + vrow * 128 + ((lg * 16) ^ swl));
      acc[jt] = __builtin_amdgcn_mfma_f32_16x16x32_bf16(pf0, vf0, acc[jt], 0, 0, 0);
      bf16x8 vf1 = *(const bf16x8*)(Vb + vrow * 128 + ((64 + lg * 16) ^ swl));
      acc[jt] = __builtin_amdgcn_mfma_f32_16x16x32_bf16(pf1, vf1, acc[jt], 0, 0, 0);
    }
    __builtin_amdgcn_s_setprio(0);
    cur ^= 1;
  }

  // ---- epilogue ----
  float linv[4];
#pragma unroll
  for (int r = 0; r < 4; r++) linv[r] = 1.0f / lsum[r];
  int orow_base = qt * QBLK + w * 16 + lg * 4;
#pragma unroll
  for (int jt = 0; jt < 8; jt++) {
    int col = h * Dh + jt * 16 + l16;
#pragma unroll
    for (int r = 0; r < 4; r++) {
      out[(size_t)(orow_base + r) * (H * Dh) + col] = acc[jt][r] * linv[r];
    }
  }
}

// ---- fallback (no workspace): round-2 fused path, fp32 inputs + on-the-fly rope ----
__global__ __launch_bounds__(THREADS) void attn_fb(
    const float* __restrict__ q, const float* __restrict__ kg,
    const float* __restrict__ vg, const float* __restrict__ pe,
    float* __restrict__ out) {
  __shared__ __align__(16) char KsB[KVBLK * Dh * 2];
  __shared__ __align__(16) char VtB[Dh * (KVBLK + 8) * 2];
  __shared__ __align__(16) bf16 Ps[8][16 * KVBLK];

  int bid = (int)blockIdx.x;
  int swz = (bid & 7) * (NQT * H / 8) + (bid >> 3);
  int h  = swz >> 5;
  int qt = swz & 31;
  int tid = threadIdx.x;
  int w = tid >> 6, lane = tid & 63;
  int l16 = lane & 15, lg = lane >> 4;

  const float SC = 0.08838834764831845f * 1.4426950408889634f;

  int qr = qt * QBLK + w * 16 + l16;
  bf16x8 qf[4];
  {
    const float* qrow  = q  + ((size_t)h * L + qr) * Dh;
    const float* perow = pe + (size_t)qr * Dh;
#pragma unroll
    for (int kk = 0; kk < 4; kk++) {
      int d = kk * 32 + lg * 8;
      float4 a  = *(const float4*)(qrow + d);
      float4 b  = *(const float4*)(qrow + d + 4);
      float4 ca = *(const float4*)(perow + d);
      float4 cb = *(const float4*)(perow + d + 4);
      float o[8]; rope4(a, ca, o); rope4(b, cb, o + 4);
#pragma unroll
      for (int j = 0; j < 8; j++) qf[kk][j] = (bf16)(o[j] * SC);
    }
  }

  float m[4], lsum[4];
  f32x4 acc[8];
#pragma unroll
  for (int r = 0; r < 4; r++) { m[r] = -3.0e38f; lsum[r] = 0.f; }
#pragma unroll
  for (int j = 0; j < 8; j++) acc[j] = (f32x4){0.f, 0.f, 0.f, 0.f};

  int krow_s = tid >> 3;
  int kd_s   = (tid & 7) * 16;
  int vd_s   = (tid & 31) * 4;
  int vp_s   = tid >> 5;
  char* psb = (char*)&Ps[w][0];

  for (int t = 0; t < NKT; t++) {
    int kv0 = t * KVBLK;
    {
      bf16 ko[16];
      const float* src = kg + ((size_t)h * L + kv0 + krow_s) * Dh + kd_s;
      const float* ps  = pe + (size_t)(kv0 + krow_s) * Dh + kd_s;
#pragma unroll
      for (int c = 0; c < 4; c++) {
        float4 a  = *(const float4*)(src + c * 4);
        float4 cs = *(const float4*)(ps + c * 4);
        float o[4]; rope4(a, cs, o);
        ko[c*4+0]=(bf16)o[0]; ko[c*4+1]=(bf16)o[1];
        ko[c*4+2]=(bf16)o[2]; ko[c*4+3]=(bf16)o[3];
      }
#pragma unroll
      for (int c = 0; c < 2; c++) {
        int byte = (krow_s * 256 + (kd_s + c * 8) * 2) ^ ((krow_s & 7) << 4);
        *(bf16x8*)(KsB + byte) = *(bf16x8*)(ko + c * 8);
      }
    }
#pragma unroll
    for (int pi = 0; pi < 2; pi++) {
      int p = vp_s + pi * 16;
      int r0 = 2 * p;
      float4 fa = *(const float4*)(vg + ((size_t)h * L + kv0 + r0)     * Dh + vd_s);
      float4 fb = *(const float4*)(vg + ((size_t)h * L + kv0 + r0 + 1) * Dh + vd_s);
      bf16x4 a4, b4;
      a4[0]=(bf16)fa.x; a4[1]=(bf16)fa.y; a4[2]=(bf16)fa.z; a4[3]=(bf16)fa.w;
      b4[0]=(bf16)fb.x; b4[1]=(bf16)fb.y; b4[2]=(bf16)fb.z; b4[3]=(bf16)fb.w;
#pragma unroll
      for (int j = 0; j < 4; j++) {
        bf16x2 pr; pr[0] = a4[j]; pr[1] = b4[j];
        *(bf16x2*)(VtB + (vd_s + j) * 144 + r0 * 2) = pr;
      }
    }
    __syncthreads();

    f32x4 s[4];
#pragma unroll
    for (int jt = 0; jt < 4; jt++) {
      f32x4 a_s = (f32x4){0.f, 0.f, 0.f, 0.f};
      int krow = jt * 16 + l16;
#pragma unroll
      for (int kk = 0; kk < 4; kk++) {
        int byte = (krow * 256 + kk * 64 + lg * 16) ^ ((krow & 7) << 4);
        bf16x8 kf = *(const bf16x8*)(KsB + byte);
        a_s = __builtin_amdgcn_mfma_f32_16x16x32_bf16(qf[kk], kf, a_s, 0, 0, 0);
      }
      s[jt] = a_s;
    }

#pragma unroll
    for (int r = 0; r < 4; r++) {
      float tm = fmaxf(fmaxf(s[0][r], s[1][r]), fmaxf(s[2][r], s[3][r]));
#pragma unroll
      for (int off = 1; off < 16; off <<= 1) tm = fmaxf(tm, __shfl_xor(tm, off, 64));
      float mn = fmaxf(m[r], tm);
      float alpha = exp2f(m[r] - mn);
      m[r] = mn;
      float rs = 0.f;
#pragma unroll
      for (int jt = 0; jt < 4; jt++) {
        float pv_ = exp2f(s[jt][r] - mn);
        s[jt][r] = pv_;
        rs += pv_;
      }
#pragma unroll
      for (int off = 1; off < 16; off <<= 1) rs += __shfl_xor(rs, off, 64);
      lsum[r] = lsum[r] * alpha + rs;
#pragma unroll
      for (int j = 0; j < 8; j++) acc[j][r] *= alpha;
    }

#pragma unroll
    for (int jt = 0; jt < 4; jt++)
#pragma unroll
      for (int r = 0; r < 4; r++) {
        int row = lg * 4 + r;
        int byte = (row * 128 + (jt * 16 + l16) * 2) ^ ((row & 7) << 4);
        *(bf16*)(psb + byte) = (bf16)s[jt][r];
      }
    asm volatile("s_waitcnt lgkmcnt(0)" ::: "memory");
    int pb0 = (l16 * 128 + lg * 16) ^ ((l16 & 7) << 4);
    int pb1 = (l16 * 128 + 64 + lg * 16) ^ ((l16 & 7) << 4);
    bf16x8 pf0 = *(const bf16x8*)(psb + pb0);
    bf16x8 pf1 = *(const bf16x8*)(psb + pb1);

#pragma unroll
    for (int jt = 0; jt < 8; jt++) {
      bf16x8 vf0 = *(const bf16x8*)(VtB + (jt * 16 + l16) * 144 + (lg * 8) * 2);
      acc[jt] = __builtin_amdgcn_mfma_f32_16x16x32_bf16(pf0, vf0, acc[jt], 0, 0, 0);
      bf16x8 vf1 = *(const bf16x8*)(VtB + (jt * 16 + l16) * 144 + (32 + lg * 8) * 2);
      acc[jt] = __builtin_amdgcn_mfma_f32_16x16x32_bf16(pf1, vf1, acc[jt], 0, 0, 0);
    }
    __syncthreads();
  }

  float linv[4];
#pragma unroll
  for (int r = 0; r < 4; r++) linv[r] = 1.0f / lsum[r];
  int orow_base = qt * QBLK + w * 16 + lg * 4;
#pragma unroll
  for (int jt = 0; jt < 8; jt++) {
    int col = h * Dh + jt * 16 + l16;
#pragma unroll
    for (int r = 0; r < 4; r++) {
      out[(size_t)(orow_base + r) * (H * Dh) + col] = acc[jt][r] * linv[r];
    }
  }
}

extern "C" void kernel_launch(void* const* d_in, const int* in_sizes, int n_in,
                              void* d_out, int out_size, void* d_ws, size_t ws_size,
                              hipStream_t stream) {
  const float* q  = (const float*)d_in[0];
  const float* k  = (const float*)d_in[1];
  const float* v  = (const float*)d_in[2];
  const float* pe = (const float*)d_in[3];
  float* out = (float*)d_out;
  const size_t elems = (size_t)H * L * Dh;
  const size_t need  = 2 * elems * sizeof(unsigned short);
  if (ws_size >= need) {
    bf16* wk = (bf16*)d_ws;
    bf16* wv = wk + elems;
    prep_kernel<<<(int)(elems / 8 / 256), 256, 0, stream>>>(k, pe, wk);
    vtrans_kernel<<<H * (L / 64) * (Dh / 64), 256, 0, stream>>>(v, wv);
    attn_pipe<<<H * NQT, THREADS, 0, stream>>>(q, pe, wk, wv, out);
  } else {
    attn_fb<<<H * NQT, THREADS, 0, stream>>>(q, k, v, pe, out);
  }
}

// Round 4
// 310.233 us; speedup vs baseline: 2.2244x; 1.6057x over previous
//
#include <hip/hip_runtime.h>
#include <hip/hip_bf16.h>

#define H 24
#define L 4096
#define Dh 128
#define QBLK 128
#define KVBLK 64
#define NQT (L/QBLK)        // 32
#define NKT (L/KVBLK)       // 64

typedef __bf16 bf16;
typedef bf16 bf16x8 __attribute__((ext_vector_type(8)));
typedef bf16 bf16x4 __attribute__((ext_vector_type(4)));
typedef bf16 bf16x2 __attribute__((ext_vector_type(2)));
typedef float f32x4 __attribute__((ext_vector_type(4)));
typedef float f32x16 __attribute__((ext_vector_type(16)));
typedef unsigned u32x4 __attribute__((ext_vector_type(4)));

__device__ __forceinline__ void rope4(const float4& x, const float4& cs, float* o) {
  o[0] = x.x*cs.x - x.y*cs.y;
  o[1] = x.x*cs.y + x.y*cs.x;
  o[2] = x.z*cs.z - x.w*cs.w;
  o[3] = x.z*cs.w + x.w*cs.z;
}

__device__ __forceinline__ unsigned cvt_pk_bf16(float lo, float hi_) {
  unsigned r;
  asm("v_cvt_pk_bf16_f32 %0, %1, %2" : "=v"(r) : "v"(lo), "v"(hi_));
  return r;
}

__device__ __forceinline__ void pl_swap(unsigned &a, unsigned &b) {
#if __has_builtin(__builtin_amdgcn_permlane32_swap)
  typedef unsigned u32x2_t __attribute__((ext_vector_type(2)));
  u32x2_t r = __builtin_amdgcn_permlane32_swap(a, b, false, false);
  a = r.x; b = r.y;
#else
  asm("v_permlane32_swap_b32 %0, %1" : "+v"(a), "+v"(b));
#endif
}

// Pack 8 P-values (C/D regs BASE..BASE+7) into the A-fragment for one 16-kv slice.
// After swap: a0=[own g][partner g+1], etc. -> frag words in row order for both halves.
template<int BASE>
__device__ __forceinline__ bf16x8 pack_frag(const f32x16& s) {
  unsigned a0 = cvt_pk_bf16(s[BASE+0], s[BASE+1]);
  unsigned a1 = cvt_pk_bf16(s[BASE+2], s[BASE+3]);
  unsigned b0 = cvt_pk_bf16(s[BASE+4], s[BASE+5]);
  unsigned b1 = cvt_pk_bf16(s[BASE+6], s[BASE+7]);
  pl_swap(a0, b0);
  pl_swap(a1, b1);
  u32x4 v; v[0] = a0; v[1] = a1; v[2] = b0; v[3] = b1;
  return __builtin_bit_cast(bf16x8, v);
}

__device__ __forceinline__ f32x16 zero16() {
  f32x16 v;
#pragma unroll
  for (int i = 0; i < 16; i++) v[i] = 0.f;
  return v;
}

// K-prep: RoPE(K) -> bf16, MFMA-A-fragment order.
// wk chunk ((h*128+B)*8+ks): lane l bytes l*16 = K[h][B*32+(l&31)][ks*16+(l>>5)*8 + 0..7]
__global__ __launch_bounds__(256) void kprep(const float* __restrict__ k,
    const float* __restrict__ pe, bf16* __restrict__ wk) {
  int b = blockIdx.x;            // h*128 + B
  int h = b >> 7;
  int t = threadIdx.x;
  int l = t & 63, wq = t >> 6, hi = l >> 5;
  int row = (b & 127) * 32 + (l & 31);
  const float* kr = k + ((size_t)h * L + row) * Dh;
  const float* pr = pe + (size_t)row * Dh;
#pragma unroll
  for (int i = 0; i < 2; i++) {
    int ks = wq * 2 + i;
    int d = ks * 16 + hi * 8;
    float4 a  = *(const float4*)(kr + d);
    float4 c  = *(const float4*)(pr + d);
    float4 a2 = *(const float4*)(kr + d + 4);
    float4 c2 = *(const float4*)(pr + d + 4);
    float o[8]; rope4(a, c, o); rope4(a2, c2, o + 4);
    bf16x8 r;
#pragma unroll
    for (int j = 0; j < 8; j++) r[j] = (bf16)o[j];
    *(bf16x8*)(wk + ((size_t)b * 8 + ks) * 512 + l * 8) = r;
  }
}

// V-prep: V -> bf16, MFMA-B-fragment order.
// wv chunk ((h*256+S)*4+dt): lane l = V[h][S*16+(l>>5)*8+j][dt*32+(l&31)]
__global__ __launch_bounds__(256) void vprep(const float* __restrict__ v,
    bf16* __restrict__ wv) {
  __shared__ bf16 T[64][132];    // 264B row stride
  int b = blockIdx.x;            // h*64 + G
  int h = b >> 6, G = b & 63;
  int t = threadIdx.x;
  {
    int row = t >> 2, c0 = (t & 3) * 32;
    const float* src = v + ((size_t)h * L + G * 64 + row) * Dh + c0;
#pragma unroll
    for (int i = 0; i < 8; i++) {
      float4 a = ((const float4*)src)[i];
      T[row][c0 + i*4 + 0] = (bf16)a.x; T[row][c0 + i*4 + 1] = (bf16)a.y;
      T[row][c0 + i*4 + 2] = (bf16)a.z; T[row][c0 + i*4 + 3] = (bf16)a.w;
    }
  }
  __syncthreads();
  int l = t & 63, wq = t >> 6, hi = l >> 5, l31 = l & 31;
#pragma unroll
  for (int dt = 0; dt < 4; dt++) {
    bf16x8 r;
#pragma unroll
    for (int j = 0; j < 8; j++) r[j] = T[wq * 16 + hi * 8 + j][dt * 32 + l31];
    *(bf16x8*)(wv + (((size_t)h * 256 + G * 4 + wq) * 4 + dt) * 512 + l * 8) = r;
  }
}

// ---- flash attention: 4 waves x 32 q-rows, 32x32x16 MFMA, swapped QK^T,
// in-register softmax + P-frag build (cvt_pk + permlane32_swap), frag-ordered
// LDS (conflict-free), double-buffered, 1 barrier/iter, defer-max. ----
__global__ __launch_bounds__(256, 2) void attn2(
    const float* __restrict__ q, const float* __restrict__ pe,
    const bf16* __restrict__ wk, const bf16* __restrict__ wv,
    float* __restrict__ out) {
  __shared__ __align__(16) char Kb2[2][16384];
  __shared__ __align__(16) char Vb2[2][16384];

  int bid = (int)blockIdx.x;
  int swz = (bid & 7) * (H * NQT / 8) + (bid >> 3);
  int h = swz >> 5, qt = swz & 31;
  int tid = threadIdx.x;
  int w = tid >> 6, lane = tid & 63;
  int l31 = lane & 31, hi = lane >> 5;

  const float SC = 0.08838834764831845f * 1.4426950408889634f; // 1/sqrt(128)*log2e

  // ---- Q B-fragments (rope + scale once): qf[ks][j] = Q[q][ks*16+hi*8+j]*SC ----
  int qrow = qt * QBLK + w * 32 + l31;
  bf16x8 qf[8];
  {
    const float* qp = q + ((size_t)h * L + qrow) * Dh;
    const float* pp = pe + (size_t)qrow * Dh;
#pragma unroll
    for (int ks = 0; ks < 8; ks++) {
      int d = ks * 16 + hi * 8;
      float4 a  = *(const float4*)(qp + d);
      float4 c  = *(const float4*)(pp + d);
      float4 a2 = *(const float4*)(qp + d + 4);
      float4 c2 = *(const float4*)(pp + d + 4);
      float o[8]; rope4(a, c, o); rope4(a2, c2, o + 4);
#pragma unroll
      for (int j = 0; j < 8; j++) qf[ks][j] = (bf16)(o[j] * SC);
    }
  }

  f32x16 acc[4];
#pragma unroll
  for (int dt = 0; dt < 4; dt++) acc[dt] = zero16();
  float m = -3.0e38f, lsum = 0.f;

  // ---- staging: linear 16KB copies (frag-ordered in ws) ----
  const bf16* ksrc = wk + (size_t)h * 524288 + tid * 8;
  const bf16* vsrc = wv + (size_t)h * 524288 + tid * 8;
  bf16x8 sk[4], sv[4];
#pragma unroll
  for (int i = 0; i < 4; i++) {
    sk[i] = *(const bf16x8*)(ksrc + i * 2048);
    sv[i] = *(const bf16x8*)(vsrc + i * 2048);
  }
  ksrc += 8192; vsrc += 8192;

  int cur = 0;
  for (int t = 0; t < NKT; t++) {
    bf16* kb = (bf16*)Kb2[cur];
    bf16* vb = (bf16*)Vb2[cur];
#pragma unroll
    for (int i = 0; i < 4; i++) *(bf16x8*)(kb + tid * 8 + i * 2048) = sk[i];
#pragma unroll
    for (int i = 0; i < 4; i++) *(bf16x8*)(vb + tid * 8 + i * 2048) = sv[i];
    if (t + 1 < NKT) {
#pragma unroll
      for (int i = 0; i < 4; i++) {
        sk[i] = *(const bf16x8*)(ksrc + i * 2048);
        sv[i] = *(const bf16x8*)(vsrc + i * 2048);
      }
      ksrc += 8192; vsrc += 8192;
    }
    // barrier needs only LDS writes drained; global loads stay in flight
    asm volatile("s_waitcnt lgkmcnt(0)" ::: "memory");
    __builtin_amdgcn_s_barrier();
    __builtin_amdgcn_sched_barrier(0);

    // ---- QK^T (swapped): st[kvt] = K_tile . Q^T ; rows=kv, cols=q ----
    f32x16 st0 = zero16(), st1 = zero16();
    __builtin_amdgcn_s_setprio(1);
#pragma unroll
    for (int ks = 0; ks < 8; ks++) {
      bf16x8 k0 = *(const bf16x8*)(kb + (0 * 8 + ks) * 512 + lane * 8);
      st0 = __builtin_amdgcn_mfma_f32_32x32x16_bf16(k0, qf[ks], st0, 0, 0, 0);
      bf16x8 k1 = *(const bf16x8*)(kb + (1 * 8 + ks) * 512 + lane * 8);
      st1 = __builtin_amdgcn_mfma_f32_32x32x16_bf16(k1, qf[ks], st1, 0, 0, 0);
    }
    __builtin_amdgcn_s_setprio(0);

    // ---- in-register online softmax (exp2 domain, defer-max THR=8) ----
    float t8[8];
#pragma unroll
    for (int i = 0; i < 8; i++)
      t8[i] = fmaxf(fmaxf(st0[i], st0[i + 8]), fmaxf(st1[i], st1[i + 8]));
#pragma unroll
    for (int i = 0; i < 4; i++) t8[i] = fmaxf(t8[i], t8[i + 4]);
    float tm = fmaxf(fmaxf(t8[0], t8[1]), fmaxf(t8[2], t8[3]));
    tm = fmaxf(tm, __shfl_xor(tm, 32, 64));
    if (__any(tm > m + 8.f)) {
      float mn = fmaxf(m, tm);
      float alpha = exp2f(m - mn);
      m = mn;
      lsum *= alpha;
#pragma unroll
      for (int r = 0; r < 16; r++) {
        int cr = (r & 3) + 8 * (r >> 2) + 4 * hi;
        float ar = __shfl(alpha, cr, 64);
#pragma unroll
        for (int dt = 0; dt < 4; dt++) acc[dt][r] *= ar;
      }
    }
#pragma unroll
    for (int r = 0; r < 16; r++) {
      st0[r] = exp2f(st0[r] - m);
      st1[r] = exp2f(st1[r] - m);
    }
    {
      float s8[8];
#pragma unroll
      for (int i = 0; i < 8; i++) s8[i] = (st0[i] + st0[i + 8]) + (st1[i] + st1[i + 8]);
#pragma unroll
      for (int i = 0; i < 4; i++) s8[i] += s8[i + 4];
      float rs = (s8[0] + s8[1]) + (s8[2] + s8[3]);
      rs += __shfl_xor(rs, 32, 64);
      lsum += rs;
    }

    // ---- P -> A-fragments, fully in-register ----
    bf16x8 pa00 = pack_frag<0>(st0);   // kv  0..15
    bf16x8 pa01 = pack_frag<8>(st0);   // kv 16..31
    bf16x8 pa10 = pack_frag<0>(st1);   // kv 32..47
    bf16x8 pa11 = pack_frag<8>(st1);   // kv 48..63

    // ---- PV: acc[dt] += P . V ----
    __builtin_amdgcn_s_setprio(1);
#pragma unroll
    for (int dt = 0; dt < 4; dt++) {
      bf16x8 v0 = *(const bf16x8*)(vb + (0 * 4 + dt) * 512 + lane * 8);
      acc[dt] = __builtin_amdgcn_mfma_f32_32x32x16_bf16(pa00, v0, acc[dt], 0, 0, 0);
      bf16x8 v1 = *(const bf16x8*)(vb + (1 * 4 + dt) * 512 + lane * 8);
      acc[dt] = __builtin_amdgcn_mfma_f32_32x32x16_bf16(pa01, v1, acc[dt], 0, 0, 0);
      bf16x8 v2 = *(const bf16x8*)(vb + (2 * 4 + dt) * 512 + lane * 8);
      acc[dt] = __builtin_amdgcn_mfma_f32_32x32x16_bf16(pa10, v2, acc[dt], 0, 0, 0);
      bf16x8 v3 = *(const bf16x8*)(vb + (3 * 4 + dt) * 512 + lane * 8);
      acc[dt] = __builtin_amdgcn_mfma_f32_32x32x16_bf16(pa11, v3, acc[dt], 0, 0, 0);
    }
    __builtin_amdgcn_s_setprio(0);
    cur ^= 1;
  }

  // ---- epilogue: normalize + write (L, H*D) ----
#pragma unroll
  for (int r = 0; r < 16; r++) {
    int cr = (r & 3) + 8 * (r >> 2) + 4 * hi;
    float ls = __shfl(lsum, cr, 64);
    float inv = 1.0f / ls;
    size_t orow = (size_t)(qt * QBLK + w * 32 + cr);
    float* op = out + orow * (H * Dh) + h * Dh + l31;
#pragma unroll
    for (int dt = 0; dt < 4; dt++) op[dt * 32] = acc[dt][r] * inv;
  }
}

// ---- fallback (no workspace): round-3 fused path ----
__global__ __launch_bounds__(512) void attn_fb(
    const float* __restrict__ q, const float* __restrict__ kg,
    const float* __restrict__ vg, const float* __restrict__ pe,
    float* __restrict__ out) {
  __shared__ __align__(16) char KsB[KVBLK * Dh * 2];
  __shared__ __align__(16) char VtB[Dh * (KVBLK + 8) * 2];
  __shared__ __align__(16) bf16 Ps[8][16 * KVBLK];

  int bid = (int)blockIdx.x;
  int swz = (bid & 7) * (NQT * H / 8) + (bid >> 3);
  int h  = swz >> 5;
  int qt = swz & 31;
  int tid = threadIdx.x;
  int w = tid >> 6, lane = tid & 63;
  int l16 = lane & 15, lg = lane >> 4;

  const float SC = 0.08838834764831845f * 1.4426950408889634f;

  int qr = qt * QBLK + w * 16 + l16;
  bf16x8 qf[4];
  {
    const float* qrow  = q  + ((size_t)h * L + qr) * Dh;
    const float* perow = pe + (size_t)qr * Dh;
#pragma unroll
    for (int kk = 0; kk < 4; kk++) {
      int d = kk * 32 + lg * 8;
      float4 a  = *(const float4*)(qrow + d);
      float4 b  = *(const float4*)(qrow + d + 4);
      float4 ca = *(const float4*)(perow + d);
      float4 cb = *(const float4*)(perow + d + 4);
      float o[8]; rope4(a, ca, o); rope4(b, cb, o + 4);
#pragma unroll
      for (int j = 0; j < 8; j++) qf[kk][j] = (bf16)(o[j] * SC);
    }
  }

  float m[4], lsum[4];
  f32x4 acc[8];
#pragma unroll
  for (int r = 0; r < 4; r++) { m[r] = -3.0e38f; lsum[r] = 0.f; }
#pragma unroll
  for (int j = 0; j < 8; j++) acc[j] = (f32x4){0.f, 0.f, 0.f, 0.f};

  int krow_s = tid >> 3;
  int kd_s   = (tid & 7) * 16;
  int vd_s   = (tid & 31) * 4;
  int vp_s   = tid >> 5;
  char* psb = (char*)&Ps[w][0];

  for (int t = 0; t < NKT; t++) {
    int kv0 = t * KVBLK;
    {
      bf16 ko[16];
      const float* src = kg + ((size_t)h * L + kv0 + krow_s) * Dh + kd_s;
      const float* ps  = pe + (size_t)(kv0 + krow_s) * Dh + kd_s;
#pragma unroll
      for (int c = 0; c < 4; c++) {
        float4 a  = *(const float4*)(src + c * 4);
        float4 cs = *(const float4*)(ps + c * 4);
        float o[4]; rope4(a, cs, o);
        ko[c*4+0]=(bf16)o[0]; ko[c*4+1]=(bf16)o[1];
        ko[c*4+2]=(bf16)o[2]; ko[c*4+3]=(bf16)o[3];
      }
#pragma unroll
      for (int c = 0; c < 2; c++) {
        int byte = (krow_s * 256 + (kd_s + c * 8) * 2) ^ ((krow_s & 7) << 4);
        *(bf16x8*)(KsB + byte) = *(bf16x8*)(ko + c * 8);
      }
    }
#pragma unroll
    for (int pi = 0; pi < 2; pi++) {
      int p = vp_s + pi * 16;
      int r0 = 2 * p;
      float4 fa = *(const float4*)(vg + ((size_t)h * L + kv0 + r0)     * Dh + vd_s);
      float4 fb = *(const float4*)(vg + ((size_t)h * L + kv0 + r0 + 1) * Dh + vd_s);
      bf16x4 a4, b4;
      a4[0]=(bf16)fa.x; a4[1]=(bf16)fa.y; a4[2]=(bf16)fa.z; a4[3]=(bf16)fa.w;
      b4[0]=(bf16)fb.x; b4[1]=(bf16)fb.y; b4[2]=(bf16)fb.z; b4[3]=(bf16)fb.w;
#pragma unroll
      for (int j = 0; j < 4; j++) {
        bf16x2 pr; pr[0] = a4[j]; pr[1] = b4[j];
        *(bf16x2*)(VtB + (vd_s + j) * 144 + r0 * 2) = pr;
      }
    }
    __syncthreads();

    f32x4 s[4];
#pragma unroll
    for (int jt = 0; jt < 4; jt++) {
      f32x4 a_s = (f32x4){0.f, 0.f, 0.f, 0.f};
      int krow = jt * 16 + l16;
#pragma unroll
      for (int kk = 0; kk < 4; kk++) {
        int byte = (krow * 256 + kk * 64 + lg * 16) ^ ((krow & 7) << 4);
        bf16x8 kf = *(const bf16x8*)(KsB + byte);
        a_s = __builtin_amdgcn_mfma_f32_16x16x32_bf16(qf[kk], kf, a_s, 0, 0, 0);
      }
      s[jt] = a_s;
    }

#pragma unroll
    for (int r = 0; r < 4; r++) {
      float tm = fmaxf(fmaxf(s[0][r], s[1][r]), fmaxf(s[2][r], s[3][r]));
#pragma unroll
      for (int off = 1; off < 16; off <<= 1) tm = fmaxf(tm, __shfl_xor(tm, off, 64));
      float mn = fmaxf(m[r], tm);
      float alpha = exp2f(m[r] - mn);
      m[r] = mn;
      float rs = 0.f;
#pragma unroll
      for (int jt = 0; jt < 4; jt++) {
        float pv_ = exp2f(s[jt][r] - mn);
        s[jt][r] = pv_;
        rs += pv_;
      }
#pragma unroll
      for (int off = 1; off < 16; off <<= 1) rs += __shfl_xor(rs, off, 64);
      lsum[r] = lsum[r] * alpha + rs;
#pragma unroll
      for (int j = 0; j < 8; j++) acc[j][r] *= alpha;
    }

#pragma unroll
    for (int jt = 0; jt < 4; jt++)
#pragma unroll
      for (int r = 0; r < 4; r++) {
        int row = lg * 4 + r;
        int byte = (row * 128 + (jt * 16 + l16) * 2) ^ ((row & 7) << 4);
        *(bf16*)(psb + byte) = (bf16)s[jt][r];
      }
    asm volatile("s_waitcnt lgkmcnt(0)" ::: "memory");
    int pb0 = (l16 * 128 + lg * 16) ^ ((l16 & 7) << 4);
    int pb1 = (l16 * 128 + 64 + lg * 16) ^ ((l16 & 7) << 4);
    bf16x8 pf0 = *(const bf16x8*)(psb + pb0);
    bf16x8 pf1 = *(const bf16x8*)(psb + pb1);

#pragma unroll
    for (int jt = 0; jt < 8; jt++) {
      bf16x8 vf0 = *(const bf16x8*)(VtB + (jt * 16 + l16) * 144 + (lg * 8) * 2);
      acc[jt] = __builtin_amdgcn_mfma_f32_16x16x32_bf16(pf0, vf0, acc[jt], 0, 0, 0);
      bf16x8 vf1 = *(const bf16x8*)(VtB + (jt * 16 + l16) * 144 + (32 + lg * 8) * 2);
      acc[jt] = __builtin_amdgcn_mfma_f32_16x16x32_bf16(pf1, vf1, acc[jt], 0, 0, 0);
    }
    __syncthreads();
  }

  float linv[4];
#pragma unroll
  for (int r = 0; r < 4; r++) linv[r] = 1.0f / lsum[r];
  int orow_base = qt * QBLK + w * 16 + lg * 4;
#pragma unroll
  for (int jt = 0; jt < 8; jt++) {
    int col = h * Dh + jt * 16 + l16;
#pragma unroll
    for (int r = 0; r < 4; r++) {
      out[(size_t)(orow_base + r) * (H * Dh) + col] = acc[jt][r] * linv[r];
    }
  }
}

extern "C" void kernel_launch(void* const* d_in, const int* in_sizes, int n_in,
                              void* d_out, int out_size, void* d_ws, size_t ws_size,
                              hipStream_t stream) {
  const float* q  = (const float*)d_in[0];
  const float* k  = (const float*)d_in[1];
  const float* v  = (const float*)d_in[2];
  const float* pe = (const float*)d_in[3];
  float* out = (float*)d_out;
  const size_t elems = (size_t)H * L * Dh;
  const size_t need  = 2 * elems * sizeof(unsigned short);
  if (ws_size >= need) {
    bf16* wk = (bf16*)d_ws;
    bf16* wv = wk + elems;
    kprep<<<H * 128, 256, 0, stream>>>(k, pe, wk);
    vprep<<<H * 64, 256, 0, stream>>>(v, wv);
    attn2<<<H * NQT, 256, 0, stream>>>(q, pe, wk, wv, out);
  } else {
    attn_fb<<<H * NQT, 512, 0, stream>>>(q, k, v, pe, out);
  }
}